// Round 8
// baseline (558.648 us; speedup 1.0000x reference)
//
#include <hip/hip_runtime.h>
#include <hip/hip_bf16.h>
#include <math.h>

#define BB 4
#define LL 512
#define VV 32128
#define AVV 32000
#define DD 768
#define V4 (VV / 4)   // 8032
#define D4 (DD / 4)   // 192

// t = -ln(u), with RELATIVE accuracy preserved as u->1 (the Gumbel-winner
// region). u in [1e-6, 1-1e-6].
//  - u > 0.75: series on exact x=1-u: -ln(1-x) = x + x^2*Q(x), Q truncated at
//    x^8/10 -> rel err ~1e-7 at x=0.25.
//  - u <= 0.75: native v_log_f32 (abs err ~5e-7 -> rel err <= 1.7e-6 since t>=0.287).
__device__ __forceinline__ float neg_log_u(float u) {
    float x = 1.0f - u;                      // exact for u >= 0.5
    float q = 0.1f;                          // 1/10
    q = fmaf(q, x, 1.0f / 9.0f);
    q = fmaf(q, x, 0.125f);                  // 1/8
    q = fmaf(q, x, 1.0f / 7.0f);
    q = fmaf(q, x, 1.0f / 6.0f);
    q = fmaf(q, x, 0.2f);                    // 1/5
    q = fmaf(q, x, 0.25f);                   // 1/4
    q = fmaf(q, x, 1.0f / 3.0f);
    q = fmaf(q, x, 0.5f);                    // 1/2
    float tpoly = fmaf(x * x, q, x);         // x + x^2*Q  (x kept exact)
    float tnat  = -__logf(u);
    return (u > 0.75f) ? tpoly : tnat;
}

// key = logit - ln(-ln u). Outer log native: absolute key error ~5e-7, fine
// for argmax (E[rank flips] ~ 2048 * 4e-6 << 1).
__device__ __forceinline__ float gumbel_key(float lg, float u) {
    return lg - __logf(neg_log_u(u));
}

// ---------------- Kernel 1: per-row argmax of logits + gumbel ----------------
// One 256-thread block per (b,l) row. Two independent chains (i, i+256) for
// ILP; track winning float4 index only, resolve the element after the loop.
__global__ __launch_bounds__(256) void k_argmax(const float* __restrict__ logits,
                                                const float* __restrict__ gu,
                                                int* __restrict__ hidx) {
    const int row = blockIdx.x;
    const float4* lg4 = (const float4*)(logits + (size_t)row * VV);
    const float4* gu4 = (const float4*)(gu + (size_t)row * VV);

    float bkA = -INFINITY, bkB = -INFINITY;
    int   biA = 0, biB = 0;

    int i = threadIdx.x;
    for (; i + 256 < V4; i += 512) {
        float4 l0 = lg4[i];
        float4 u0 = gu4[i];
        float4 l1 = lg4[i + 256];
        float4 u1 = gu4[i + 256];

        float a0 = gumbel_key(l0.x, u0.x);
        float a1 = gumbel_key(l0.y, u0.y);
        float a2 = gumbel_key(l0.z, u0.z);
        float a3 = gumbel_key(l0.w, u0.w);
        float mA = fmaxf(fmaxf(a0, a1), fmaxf(a2, a3));
        if (mA > bkA) { bkA = mA; biA = i; }

        float b0 = gumbel_key(l1.x, u1.x);
        float b1 = gumbel_key(l1.y, u1.y);
        float b2 = gumbel_key(l1.z, u1.z);
        float b3 = gumbel_key(l1.w, u1.w);
        float mB = fmaxf(fmaxf(b0, b1), fmaxf(b2, b3));
        if (mB > bkB) { bkB = mB; biB = i + 256; }
    }
    if (i < V4) {   // tail float4
        float4 l0 = lg4[i];
        float4 u0 = gu4[i];
        float a0 = gumbel_key(l0.x, u0.x);
        float a1 = gumbel_key(l0.y, u0.y);
        float a2 = gumbel_key(l0.z, u0.z);
        float a3 = gumbel_key(l0.w, u0.w);
        float mA = fmaxf(fmaxf(a0, a1), fmaxf(a2, a3));
        if (mA > bkA) { bkA = mA; biA = i; }
    }

    // merge chains (strict > kept earliest within each chain; tie -> smaller idx)
    float bk; int bi;
    if (bkB > bkA || (bkB == bkA && biB < biA)) { bk = bkB; bi = biB; }
    else                                        { bk = bkA; bi = biA; }

    // resolve element within the winning float4 (recompute is bit-identical)
    {
        float4 lv = lg4[bi];
        float4 uv = gu4[bi];
        float k0 = gumbel_key(lv.x, uv.x);
        float k1 = gumbel_key(lv.y, uv.y);
        float k2 = gumbel_key(lv.z, uv.z);
        int j = (k0 == bk) ? 0 : ((k1 == bk) ? 1 : ((k2 == bk) ? 2 : 3));
        bi = bi * 4 + j;
    }

    // wave (64-lane) reduction; tie -> smaller index
    for (int off = 32; off > 0; off >>= 1) {
        float ok = __shfl_down(bk, off);
        int   oi = __shfl_down(bi, off);
        if (ok > bk || (ok == bk && oi < bi)) { bk = ok; bi = oi; }
    }

    __shared__ float sk[4];
    __shared__ int   si[4];
    const int wid = threadIdx.x >> 6;
    if ((threadIdx.x & 63) == 0) { sk[wid] = bk; si[wid] = bi; }
    __syncthreads();
    if (threadIdx.x == 0) {
        for (int w = 1; w < 4; ++w) {
            if (sk[w] > bk || (sk[w] == bk && si[w] < bi)) { bk = sk[w]; bi = si[w]; }
        }
        hidx[row] = bi;
    }
}

// ---------------- Kernel 2: per-(b,l) token selection ----------------
__global__ __launch_bounds__(512) void k_tokens(const int* __restrict__ rwrt,
                                                const int* __restrict__ psg_in,
                                                const int* __restrict__ hidx,
                                                int2* __restrict__ toks) {
    __shared__ int s[LL];
    const int b = blockIdx.x;
    const int l = threadIdx.x;

    const int rw = rwrt[b * LL + l];

    // shifts = sum(rwrt == 1)
    s[l] = (rw == 1) ? 1 : 0;
    __syncthreads();
    for (int off = LL / 2; off > 0; off >>= 1) {
        if (l < off) s[l] += s[l + off];
        __syncthreads();
    }
    const int shifts = s[0];
    __syncthreads();

    const int pos = (l - shifts) & (LL - 1);
    const int psgv = (pos == 0) ? 1 : psg_in[b * LL + pos - 1];
    const int flip = 1 - rwrt[b * LL + (LL - 1 - pos)];
    const int trunc = flip * psgv;

    // flag = inclusive OR-scan of (trunc != 0), Hillis-Steele
    s[l] = (trunc != 0) ? 1 : 0;
    __syncthreads();
    for (int off = 1; off < LL; off <<= 1) {
        int v = (l >= off) ? s[l - off] : 0;
        __syncthreads();
        s[l] |= v;
        __syncthreads();
    }
    const int flag = s[l];

    const int h = hidx[b * LL + l];
    const int tokA = (rw != 0 && h < AVV) ? h : -1;
    const int tokP = flag ? trunc : -1;
    toks[b * LL + l] = make_int2(tokA, tokP);
}

// ---------------- Kernel 3: gather embeddings, sum, store f32 ----------------
__global__ __launch_bounds__(192) void k_out(const float* __restrict__ emb,
                                             const int2* __restrict__ toks,
                                             float* __restrict__ out) {
    const int row = blockIdx.x;
    const int t = threadIdx.x;
    const int2 tk = toks[row];

    float4 acc = make_float4(0.f, 0.f, 0.f, 0.f);
    if (tk.x >= 0) {
        float4 e = ((const float4*)(emb + (size_t)tk.x * DD))[t];
        acc.x += e.x; acc.y += e.y; acc.z += e.z; acc.w += e.w;
    }
    if (tk.y >= 0) {
        float4 e = ((const float4*)(emb + (size_t)tk.y * DD))[t];
        acc.x += e.x; acc.y += e.y; acc.z += e.z; acc.w += e.w;
    }
    ((float4*)out)[(size_t)row * D4 + t] = acc;   // OUTPUT IS FLOAT32
}

extern "C" void kernel_launch(void* const* d_in, const int* in_sizes, int n_in,
                              void* d_out, int out_size, void* d_ws, size_t ws_size,
                              hipStream_t stream) {
    const float* logits = (const float*)d_in[0];
    const float* gu     = (const float*)d_in[1];
    const float* emb    = (const float*)d_in[2];
    const int*   rwrt   = (const int*)d_in[3];
    const int*   psg    = (const int*)d_in[4];
    float* out = (float*)d_out;

    int*  hidx = (int*)d_ws;
    int2* toks = (int2*)((char*)d_ws + BB * LL * sizeof(int));

    k_argmax<<<BB * LL, 256, 0, stream>>>(logits, gu, hidx);
    k_tokens<<<BB, LL, 0, stream>>>(rwrt, psg, hidx, toks);
    k_out<<<BB * LL, 192, 0, stream>>>(emb, toks, out);
}

// Round 9
// 554.657 us; speedup vs baseline: 1.0072x; 1.0072x over previous
//
#include <hip/hip_runtime.h>
#include <hip/hip_bf16.h>
#include <math.h>

#define BB 4
#define LL 512
#define VV 32128
#define AVV 32000
#define DD 768
#define V4 (VV / 4)   // 8032
#define D4 (DD / 4)   // 192

// ---- exact key path (identical numerics to the R8 kernel that passed) ----
// t = -ln(u), RELATIVE accuracy preserved as u->1.
__device__ __forceinline__ float neg_log_u(float u) {
    float x = 1.0f - u;
    float q = 0.1f;
    q = fmaf(q, x, 1.0f / 9.0f);
    q = fmaf(q, x, 0.125f);
    q = fmaf(q, x, 1.0f / 7.0f);
    q = fmaf(q, x, 1.0f / 6.0f);
    q = fmaf(q, x, 0.2f);
    q = fmaf(q, x, 0.25f);
    q = fmaf(q, x, 1.0f / 3.0f);
    q = fmaf(q, x, 0.5f);
    float tpoly = fmaf(x * x, q, x);
    float tnat  = -__logf(u);
    return (u > 0.75f) ? tpoly : tnat;
}
__device__ __forceinline__ float gumbel_key(float lg, float u) {
    return lg - __logf(neg_log_u(u));
}

// ---- cheap conservative upper bound: key <= lg - ln(1-u) <= lg - ln2*bitlog2(1-u) ----
// bitlog2(x) = bits(x)*2^-23 - 127 is a LOWER bound of log2(x)  (err in [0, 0.0861])
// UB = fmaf(bits, -ln2*2^-23, lg) + (127*ln2 + margin); margin=0.05 makes pruning
// strictly conservative vs every float-rounding in play -> winner set identical.
#define UB_SCALE 8.2629583e-8f      // ln2 / 2^23
#define UB_C     88.0796919f        // 127*ln2 + 0.05
__device__ __forceinline__ float ub_core(float lg, float u) {
    float x = 1.0f - u;
    float a = (float)__float_as_int(x);    // x in [1e-6,1] -> bits positive, normal
    return fmaf(a, -UB_SCALE, lg);
}
__device__ __forceinline__ float ub4(const float4& l, const float4& u) {
    return fmaxf(fmaxf(ub_core(l.x, u.x), ub_core(l.y, u.y)),
                 fmaxf(ub_core(l.z, u.z), ub_core(l.w, u.w)));
}
// exact evaluation of one float4 block, ordered index semantics (strict >, smallest j)
__device__ __forceinline__ void exact4(const float4& lv, const float4& uv, int base,
                                       float& bk, int& bi) {
    float k0 = gumbel_key(lv.x, uv.x);
    float k1 = gumbel_key(lv.y, uv.y);
    float k2 = gumbel_key(lv.z, uv.z);
    float k3 = gumbel_key(lv.w, uv.w);
    float m = fmaxf(fmaxf(k0, k1), fmaxf(k2, k3));
    if (m > bk) {
        int j = (k0 == m) ? 0 : ((k1 == m) ? 1 : ((k2 == m) ? 2 : 3));
        bk = m; bi = base * 4 + j;
    }
}

// ---------------- Kernel 1: per-row Gumbel argmax with UB pruning ----------------
__global__ __launch_bounds__(256) void k_argmax(const float* __restrict__ logits,
                                                const float* __restrict__ gu,
                                                int* __restrict__ hidx) {
    const int row = blockIdx.x;
    const float4* lg4 = (const float4*)(logits + (size_t)row * VV);
    const float4* gu4 = (const float4*)(gu + (size_t)row * VV);

    float bk = -INFINITY;   // per-lane exact best
    int   bi = 0;
    float wbest = -INFINITY; // wave-uniform max of exact keys seen (grows only)

    int i = threadIdx.x;
    // main: 4 float4-blocks per iteration (16 elems, 128B/thread in flight)
    for (; i + 768 < V4; i += 1024) {
        float4 l0 = lg4[i];       float4 u0 = gu4[i];
        float4 l1 = lg4[i + 256]; float4 u1 = gu4[i + 256];
        float4 l2 = lg4[i + 512]; float4 u2 = gu4[i + 512];
        float4 l3 = lg4[i + 768]; float4 u3 = gu4[i + 768];

        float g = fmaxf(fmaxf(ub4(l0, u0), ub4(l1, u1)),
                        fmaxf(ub4(l2, u2), ub4(l3, u3)));
        if (__any(g > wbest - UB_C)) {          // uniform branch, no divergence
            exact4(l0, u0, i,       bk, bi);
            exact4(l1, u1, i + 256, bk, bi);
            exact4(l2, u2, i + 512, bk, bi);
            exact4(l3, u3, i + 768, bk, bi);
            float m = bk;                        // refresh wave lower bound
            for (int off = 32; off > 0; off >>= 1)
                m = fmaxf(m, __shfl_xor(m, off));
            wbest = m;
        }
    }
    // tail: single float4 blocks
    for (; i < V4; i += 256) {
        float4 l0 = lg4[i]; float4 u0 = gu4[i];
        float g = ub4(l0, u0);
        if (__any(g > wbest - UB_C)) {
            exact4(l0, u0, i, bk, bi);
            float m = bk;
            for (int off = 32; off > 0; off >>= 1)
                m = fmaxf(m, __shfl_xor(m, off));
            wbest = m;
        }
    }

    // wave (64-lane) reduction; tie -> smaller index
    for (int off = 32; off > 0; off >>= 1) {
        float ok = __shfl_down(bk, off);
        int   oi = __shfl_down(bi, off);
        if (ok > bk || (ok == bk && oi < bi)) { bk = ok; bi = oi; }
    }

    __shared__ float sk[4];
    __shared__ int   si[4];
    const int wid = threadIdx.x >> 6;
    if ((threadIdx.x & 63) == 0) { sk[wid] = bk; si[wid] = bi; }
    __syncthreads();
    if (threadIdx.x == 0) {
        for (int w = 1; w < 4; ++w) {
            if (sk[w] > bk || (sk[w] == bk && si[w] < bi)) { bk = sk[w]; bi = si[w]; }
        }
        hidx[row] = bi;
    }
}

// ---------------- Kernel 2: per-(b,l) token selection ----------------
__global__ __launch_bounds__(512) void k_tokens(const int* __restrict__ rwrt,
                                                const int* __restrict__ psg_in,
                                                const int* __restrict__ hidx,
                                                int2* __restrict__ toks) {
    __shared__ int s[LL];
    const int b = blockIdx.x;
    const int l = threadIdx.x;

    const int rw = rwrt[b * LL + l];

    s[l] = (rw == 1) ? 1 : 0;
    __syncthreads();
    for (int off = LL / 2; off > 0; off >>= 1) {
        if (l < off) s[l] += s[l + off];
        __syncthreads();
    }
    const int shifts = s[0];
    __syncthreads();

    const int pos = (l - shifts) & (LL - 1);
    const int psgv = (pos == 0) ? 1 : psg_in[b * LL + pos - 1];
    const int flip = 1 - rwrt[b * LL + (LL - 1 - pos)];
    const int trunc = flip * psgv;

    s[l] = (trunc != 0) ? 1 : 0;
    __syncthreads();
    for (int off = 1; off < LL; off <<= 1) {
        int v = (l >= off) ? s[l - off] : 0;
        __syncthreads();
        s[l] |= v;
        __syncthreads();
    }
    const int flag = s[l];

    const int h = hidx[b * LL + l];
    const int tokA = (rw != 0 && h < AVV) ? h : -1;
    const int tokP = flag ? trunc : -1;
    toks[b * LL + l] = make_int2(tokA, tokP);
}

// ---------------- Kernel 3: gather embeddings, sum, store f32 ----------------
__global__ __launch_bounds__(192) void k_out(const float* __restrict__ emb,
                                             const int2* __restrict__ toks,
                                             float* __restrict__ out) {
    const int row = blockIdx.x;
    const int t = threadIdx.x;
    const int2 tk = toks[row];

    float4 acc = make_float4(0.f, 0.f, 0.f, 0.f);
    if (tk.x >= 0) {
        float4 e = ((const float4*)(emb + (size_t)tk.x * DD))[t];
        acc.x += e.x; acc.y += e.y; acc.z += e.z; acc.w += e.w;
    }
    if (tk.y >= 0) {
        float4 e = ((const float4*)(emb + (size_t)tk.y * DD))[t];
        acc.x += e.x; acc.y += e.y; acc.z += e.z; acc.w += e.w;
    }
    ((float4*)out)[(size_t)row * D4 + t] = acc;   // OUTPUT IS FLOAT32
}

extern "C" void kernel_launch(void* const* d_in, const int* in_sizes, int n_in,
                              void* d_out, int out_size, void* d_ws, size_t ws_size,
                              hipStream_t stream) {
    const float* logits = (const float*)d_in[0];
    const float* gu     = (const float*)d_in[1];
    const float* emb    = (const float*)d_in[2];
    const int*   rwrt   = (const int*)d_in[3];
    const int*   psg    = (const int*)d_in[4];
    float* out = (float*)d_out;

    int*  hidx = (int*)d_ws;
    int2* toks = (int2*)((char*)d_ws + BB * LL * sizeof(int));

    k_argmax<<<BB * LL, 256, 0, stream>>>(logits, gu, hidx);
    k_tokens<<<BB, LL, 0, stream>>>(rwrt, psg, hidx, toks);
    k_out<<<BB * LL, 192, 0, stream>>>(emb, toks, out);
}